// Round 1
// baseline (590.596 us; speedup 1.0000x reference)
//
#include <hip/hip_runtime.h>
#include <hip/hip_bf16.h>

#define NS 2048
#define NC 4096
#define SD 1024
#define BD 512
#define NH 8
#define DK 128

typedef __bf16 bf16;
typedef __bf16 bf16x8 __attribute__((ext_vector_type(8)));
typedef __bf16 bf16x4 __attribute__((ext_vector_type(4)));
typedef float f32x4 __attribute__((ext_vector_type(4)));

__device__ __forceinline__ bf16 f2bf(float f) { return (bf16)f; }
__device__ __forceinline__ bf16x8 ld8(const bf16* p) { return *(const bf16x8*)p; }
__device__ __forceinline__ f32x4 mfma16(bf16x8 a, bf16x8 b, f32x4 c) {
  return __builtin_amdgcn_mfma_f32_16x16x32_bf16(a, b, c, 0, 0, 0);
}

// ---------------- cast f32 -> bf16, vectorized x4 ----------------
__global__ void k_cast(const float* __restrict__ in, bf16* __restrict__ out, int n4) {
  int i = blockIdx.x * blockDim.x + threadIdx.x;
  int stride = gridDim.x * blockDim.x;
  for (; i < n4; i += stride) {
    float4 v = ((const float4*)in)[i];
    bf16x4 o;
    o[0] = f2bf(v.x); o[1] = f2bf(v.y); o[2] = f2bf(v.z); o[3] = f2bf(v.w);
    ((bf16x4*)out)[i] = o;
  }
}

// ---------------- GEMM: C[m][n] = sum_k A[m][k]*B[n][k] ----------------
// A: MxK row-major bf16, B: NxK row-major bf16 (i.e. C = A @ B^T).
// BM=128 BN=64 BK=64, 256 threads = 4 waves in 2x2, wave tile 64x32.
// LDS XOR-swizzle: slot c' of row r holds global 16B-chunk (c' ^ (r&7)).
template <typename CT>
__global__ __launch_bounds__(256) void k_gemm_bt(const bf16* __restrict__ A,
                                                 const bf16* __restrict__ B,
                                                 CT* __restrict__ C,
                                                 int M, int N, int K) {
  __shared__ bf16 As[128 * 64];
  __shared__ bf16 Bs[64 * 64];
  const int tid = threadIdx.x;
  const int l = tid & 63, w = tid >> 6;
  const int g = l >> 4, r15 = l & 15;
  const int m0 = blockIdx.y * 128, n0 = blockIdx.x * 64;
  const int wm = (w >> 1) * 64, wn = (w & 1) * 32;
  f32x4 acc[4][2] = {};
  for (int k0 = 0; k0 < K; k0 += 64) {
    __syncthreads();
#pragma unroll
    for (int i = 0; i < 4; i++) {  // stage A: 128 rows x 8 chunks
      int slot = tid + i * 256;
      int row = slot >> 3, cp = slot & 7;
      int gc = cp ^ (row & 7);
      *(uint4*)(As + slot * 8) = *(const uint4*)(A + (size_t)(m0 + row) * K + k0 + gc * 8);
    }
#pragma unroll
    for (int i = 0; i < 2; i++) {  // stage B: 64 rows x 8 chunks
      int slot = tid + i * 256;
      int row = slot >> 3, cp = slot & 7;
      int gc = cp ^ (row & 7);
      *(uint4*)(Bs + slot * 8) = *(const uint4*)(B + (size_t)(n0 + row) * K + k0 + gc * 8);
    }
    __syncthreads();
#pragma unroll
    for (int kk = 0; kk < 2; kk++) {
      bf16x8 af[4], bfr[2];
#pragma unroll
      for (int mi = 0; mi < 4; mi++) {
        int row = wm + mi * 16 + r15;
        int cidx = (kk * 4 + g) ^ (row & 7);
        af[mi] = *(const bf16x8*)(As + row * 64 + cidx * 8);
      }
#pragma unroll
      for (int ni = 0; ni < 2; ni++) {
        int row = wn + ni * 16 + r15;
        int cidx = (kk * 4 + g) ^ (row & 7);
        bfr[ni] = *(const bf16x8*)(Bs + row * 64 + cidx * 8);
      }
#pragma unroll
      for (int mi = 0; mi < 4; mi++)
#pragma unroll
        for (int ni = 0; ni < 2; ni++)
          acc[mi][ni] = mfma16(af[mi], bfr[ni], acc[mi][ni]);
    }
  }
  // C/D layout: col = lane&15, row = (lane>>4)*4 + rr
#pragma unroll
  for (int mi = 0; mi < 4; mi++)
#pragma unroll
    for (int ni = 0; ni < 2; ni++)
#pragma unroll
      for (int rr = 0; rr < 4; rr++) {
        int mrow = m0 + wm + mi * 16 + g * 4 + rr;
        int ncol = n0 + wn + ni * 16 + r15;
        float v = acc[mi][ni][rr];
        if constexpr (sizeof(CT) == 4) C[(size_t)mrow * N + ncol] = v;
        else                           C[(size_t)mrow * N + ncol] = f2bf(v);
      }
}

// ---------------- transpose V (NC x SD) -> Vt (SD x NC) ----------------
__global__ __launch_bounds__(256) void k_transpose(const bf16* __restrict__ V, bf16* __restrict__ Vt) {
  __shared__ bf16 tile[32][33];
  const int t = threadIdx.x;
  const int col = t & 31, r0 = t >> 5;
  const int cbase = blockIdx.y * 32;  // over NC
  const int dbase = blockIdx.x * 32;  // over SD
#pragma unroll
  for (int i = 0; i < 4; i++) {
    int r = r0 + i * 8;
    tile[r][col] = V[(size_t)(cbase + r) * SD + dbase + col];
  }
  __syncthreads();
#pragma unroll
  for (int i = 0; i < 4; i++) {
    int r = r0 + i * 8;
    Vt[(size_t)(dbase + r) * NC + cbase + col] = tile[col][r];
  }
}

// ---------------- fused gated attention (no-max softmax, single pass) ----------------
// grid (NS/16, NH); 4 waves each own a 1024-wide c-chunk for their (s-tile, head).
// Per 32-c step: 8 score MFMA -> gate*exp -> p to swizzled LDS -> 8 PV MFMA.
// Normalization applied as post-scale; writes inv_l for the mean kernel.
__global__ __launch_bounds__(256) void k_attn(const bf16* __restrict__ Q, const bf16* __restrict__ Km,
                                              const bf16* __restrict__ Vt, const float* __restrict__ Gf,
                                              float* __restrict__ inv_l, bf16* __restrict__ Hattn) {
  __shared__ bf16 p_lds[4][512];          // per-wave 16x32 p tile (swizzled)
  __shared__ float O_red[4][16][128];     // cross-wave O reduction
  __shared__ float red[4][16];
  __shared__ float invl_s[16];
  const int tid = threadIdx.x;
  const int l = tid & 63, w = tid >> 6;
  const int g = l >> 4, r15 = l & 15;
  const int row_l = g * 4;
  const int s0 = blockIdx.x * 16;
  const int h = blockIdx.y;
  const int hoff = h * DK;
  const float scale = 0.08838834764831845f;  // 1/sqrt(128)
  bf16* pw = &p_lds[w][0];

  bf16x8 qf[4];
#pragma unroll
  for (int kk = 0; kk < 4; kk++)
    qf[kk] = ld8(Q + (size_t)(s0 + r15) * SD + hoff + kk * 32 + g * 8);

  float psum[4] = {0.f, 0.f, 0.f, 0.f};
  f32x4 oacc[8] = {};
  const int cbeg = w * 1024, cend = cbeg + 1024;
  for (int c0 = cbeg; c0 < cend; c0 += 32) {
#pragma unroll
    for (int sub = 0; sub < 2; sub++) {
      const int cb = c0 + sub * 16;
      f32x4 acc = {0.f, 0.f, 0.f, 0.f};
#pragma unroll
      for (int kk = 0; kk < 4; kk++)
        acc = mfma16(qf[kk], ld8(Km + (size_t)(cb + r15) * SD + hoff + kk * 32 + g * 8), acc);
#pragma unroll
      for (int rr = 0; rr < 4; rr++) {
        const int prow = row_l + rr;
        float gv = Gf[(size_t)(s0 + prow) * NC + cb + r15];
        float p = __expf(acc[rr] * scale * gv);
        psum[rr] += p;
        int off = (prow * 64 + (sub * 16 + r15) * 2) ^ (((prow >> 1) & 3) << 4);
        *(bf16*)((char*)pw + off) = f2bf(p);
      }
    }
    const int offr = r15 * 64 + ((g ^ ((r15 >> 1) & 3)) << 4);
    bf16x8 pf = *(const bf16x8*)((const char*)pw + offr);
#pragma unroll
    for (int nf = 0; nf < 8; nf++) {
      bf16x8 vf = ld8(Vt + (size_t)(hoff + nf * 16 + r15) * NC + c0 + g * 8);
      oacc[nf] = mfma16(pf, vf, oacc[nf]);
    }
  }
  // reduce psum across the 16 lanes that share each s-row
#pragma unroll
  for (int rr = 0; rr < 4; rr++) {
    float v = psum[rr];
    v += __shfl_xor(v, 1); v += __shfl_xor(v, 2);
    v += __shfl_xor(v, 4); v += __shfl_xor(v, 8);
    psum[rr] = v;
  }
  if (r15 == 0) {
#pragma unroll
    for (int rr = 0; rr < 4; rr++) red[w][row_l + rr] = psum[rr];
  }
  __syncthreads();
  if (tid < 16) {
    float tot = red[0][tid] + red[1][tid] + red[2][tid] + red[3][tid];
    float iv = 1.0f / tot;
    invl_s[tid] = iv;
    inv_l[(size_t)(s0 + tid) * NH + h] = iv;
  }
  __syncthreads();
  float il[4];
#pragma unroll
  for (int rr = 0; rr < 4; rr++) il[rr] = invl_s[row_l + rr];
#pragma unroll
  for (int nf = 0; nf < 8; nf++)
#pragma unroll
    for (int rr = 0; rr < 4; rr++)
      O_red[w][row_l + rr][nf * 16 + r15] = oacc[nf][rr] * il[rr];
  __syncthreads();
  {
    const int row = tid >> 4, d0 = (tid & 15) * 8;
    bf16 pk[8] __attribute__((aligned(16)));
#pragma unroll
    for (int j = 0; j < 8; j++) {
      float s = O_red[0][row][d0 + j] + O_red[1][row][d0 + j] +
                O_red[2][row][d0 + j] + O_red[3][row][d0 + j];
      pk[j] = f2bf(s);
    }
    *(uint4*)(Hattn + (size_t)(s0 + row) * SD + hoff + d0) = *(const uint4*)pk;
  }
}

// ---------------- attn.mean over heads ----------------
// grid (NC/64, NS/16); wave w owns c-subtile [c0, c0+16); heads looped, Q tile in LDS.
__global__ __launch_bounds__(256) void k_attn_mean(const bf16* __restrict__ Q, const bf16* __restrict__ Km,
                                                   const float* __restrict__ Gf, const float* __restrict__ inv_l,
                                                   float* __restrict__ out_mean) {
  __shared__ bf16 Qs[16 * 1024];  // 32 KB, row-swizzled
  const int tid = threadIdx.x;
  const int l = tid & 63, w = tid >> 6;
  const int g = l >> 4, r15 = l & 15;
  const int row_l = g * 4;
  const int s0 = blockIdx.y * 16;
  const int c0 = blockIdx.x * 64 + w * 16;
  const float scale = 0.08838834764831845f;
#pragma unroll
  for (int i = 0; i < 8; i++) {  // 2048 slots of 8 elems
    int slot = tid + i * 256;
    int row = slot >> 7, cp = slot & 127;
    int gc = cp ^ (row & 7);
    *(uint4*)(Qs + slot * 8) = *(const uint4*)(Q + (size_t)(s0 + row) * SD + gc * 8);
  }
  __syncthreads();
  float gv[4];
#pragma unroll
  for (int rr = 0; rr < 4; rr++)
    gv[rr] = Gf[(size_t)(s0 + row_l + rr) * NC + c0 + r15];
  float macc[4] = {0.f, 0.f, 0.f, 0.f};
  for (int h = 0; h < NH; h++) {
    bf16x8 qf[4];
#pragma unroll
    for (int kk = 0; kk < 4; kk++) {
      int cidx = h * 16 + kk * 4 + g;
      int slot = cidx ^ (r15 & 7);
      qf[kk] = *(const bf16x8*)(Qs + r15 * 1024 + slot * 8);
    }
    f32x4 acc = {0.f, 0.f, 0.f, 0.f};
#pragma unroll
    for (int kk = 0; kk < 4; kk++)
      acc = mfma16(qf[kk], ld8(Km + (size_t)(c0 + r15) * SD + h * DK + kk * 32 + g * 8), acc);
#pragma unroll
    for (int rr = 0; rr < 4; rr++) {
      float iv = inv_l[(size_t)(s0 + row_l + rr) * NH + h];
      macc[rr] += __expf(acc[rr] * scale * gv[rr]) * iv;
    }
  }
#pragma unroll
  for (int rr = 0; rr < 4; rr++)
    out_mean[(size_t)(s0 + row_l + rr) * NC + c0 + r15] = macc[rr] * 0.125f;
}

// ---------------- residual + LayerNorm ----------------
__global__ __launch_bounds__(256) void k_ln(const float* __restrict__ Op, const float* __restrict__ HS,
                                            const float* __restrict__ bO, const float* __restrict__ gamma,
                                            const float* __restrict__ beta, float* __restrict__ out) {
  __shared__ float rs[4][2];
  const int row = blockIdx.x, t = threadIdx.x;
  const int l = t & 63, w = t >> 6;
  float4 xo = *(const float4*)(Op + (size_t)row * SD + t * 4);
  float4 hs = *(const float4*)(HS + (size_t)row * SD + t * 4);
  float4 bo = *(const float4*)(bO + t * 4);
  float x[4] = {xo.x + hs.x + bo.x, xo.y + hs.y + bo.y,
                xo.z + hs.z + bo.z, xo.w + hs.w + bo.w};
  float s = x[0] + x[1] + x[2] + x[3];
  float q = x[0] * x[0] + x[1] * x[1] + x[2] * x[2] + x[3] * x[3];
#pragma unroll
  for (int m = 1; m < 64; m <<= 1) { s += __shfl_xor(s, m); q += __shfl_xor(q, m); }
  if (l == 0) { rs[w][0] = s; rs[w][1] = q; }
  __syncthreads();
  s = rs[0][0] + rs[1][0] + rs[2][0] + rs[3][0];
  q = rs[0][1] + rs[1][1] + rs[2][1] + rs[3][1];
  float mean = s * (1.0f / SD);
  float var = q * (1.0f / SD) - mean * mean;
  float rstd = rsqrtf(var + 1e-5f);
  float4 gm = *(const float4*)(gamma + t * 4);
  float4 bt = *(const float4*)(beta + t * 4);
  float4 o;
  o.x = (x[0] - mean) * rstd * gm.x + bt.x;
  o.y = (x[1] - mean) * rstd * gm.y + bt.y;
  o.z = (x[2] - mean) * rstd * gm.z + bt.z;
  o.w = (x[3] - mean) * rstd * gm.w + bt.w;
  *(float4*)(out + (size_t)row * SD + t * 4) = o;
}

extern "C" void kernel_launch(void* const* d_in, const int* in_sizes, int n_in,
                              void* d_out, int out_size, void* d_ws, size_t ws_size,
                              hipStream_t stream) {
  const float* H_S = (const float*)d_in[0];
  const float* H_C = (const float*)d_in[1];
  const float* G   = (const float*)d_in[2];
  const float* W_Q = (const float*)d_in[3];
  const float* W_K = (const float*)d_in[4];
  const float* W_V = (const float*)d_in[5];
  const float* W_O = (const float*)d_in[6];
  const float* b_O = (const float*)d_in[7];
  const float* gam = (const float*)d_in[8];
  const float* bet = (const float*)d_in[9];
  float* out = (float*)d_out;                     // (NS, SD)
  float* out_mean = out + (size_t)NS * SD;        // (NS, NC)

  char* p = (char*)d_ws;
  auto alloc = [&](size_t bytes) { char* r = p; p += (bytes + 255) & ~(size_t)255; return r; };
  bf16* HSb = (bf16*)alloc((size_t)NS * SD * 2);
  bf16* HCb = (bf16*)alloc((size_t)NC * BD * 2);
  bf16* WQb = (bf16*)alloc((size_t)SD * SD * 2);
  bf16* WKb = (bf16*)alloc((size_t)SD * BD * 2);
  bf16* WVb = (bf16*)alloc((size_t)SD * BD * 2);
  bf16* WOb = (bf16*)alloc((size_t)SD * SD * 2);
  bf16* Qb  = (bf16*)alloc((size_t)NS * SD * 2);
  bf16* Kb  = (bf16*)alloc((size_t)NC * SD * 2);
  bf16* Vb  = (bf16*)alloc((size_t)NC * SD * 2);
  bf16* Vtb = (bf16*)alloc((size_t)SD * NC * 2);
  bf16* Hat = (bf16*)alloc((size_t)NS * SD * 2);
  float* Opj  = (float*)alloc((size_t)NS * SD * 4);
  float* invl = (float*)alloc((size_t)NS * NH * 4);

  k_cast<<<1024, 256, 0, stream>>>(H_S, HSb, NS * SD / 4);
  k_cast<<<1024, 256, 0, stream>>>(H_C, HCb, NC * BD / 4);
  k_cast<<<1024, 256, 0, stream>>>(W_Q, WQb, SD * SD / 4);
  k_cast<<<1024, 256, 0, stream>>>(W_K, WKb, SD * BD / 4);
  k_cast<<<1024, 256, 0, stream>>>(W_V, WVb, SD * BD / 4);
  k_cast<<<1024, 256, 0, stream>>>(W_O, WOb, SD * SD / 4);

  k_gemm_bt<bf16><<<dim3(SD / 64, NS / 128), 256, 0, stream>>>(HSb, WQb, Qb, NS, SD, SD);
  k_gemm_bt<bf16><<<dim3(SD / 64, NC / 128), 256, 0, stream>>>(HCb, WKb, Kb, NC, SD, BD);
  k_gemm_bt<bf16><<<dim3(SD / 64, NC / 128), 256, 0, stream>>>(HCb, WVb, Vb, NC, SD, BD);
  k_transpose<<<dim3(SD / 32, NC / 32), 256, 0, stream>>>(Vb, Vtb);
  k_attn<<<dim3(NS / 16, NH), 256, 0, stream>>>(Qb, Kb, Vtb, G, invl, Hat);
  k_attn_mean<<<dim3(NC / 64, NS / 16), 256, 0, stream>>>(Qb, Kb, G, invl, out_mean);
  k_gemm_bt<float><<<dim3(SD / 64, NS / 128), 256, 0, stream>>>(Hat, WOb, Opj, NS, SD, SD);
  k_ln<<<NS, 256, 0, stream>>>(Opj, H_S, b_O, gam, bet, out);
}

// Round 3
// 515.953 us; speedup vs baseline: 1.1447x; 1.1447x over previous
//
#include <hip/hip_runtime.h>
#include <hip/hip_bf16.h>

#define NS 2048
#define NC 4096
#define SD 1024
#define BD 512
#define NH 8
#define DK 128

typedef __bf16 bf16;
typedef __bf16 bf16x8 __attribute__((ext_vector_type(8)));
typedef __bf16 bf16x4 __attribute__((ext_vector_type(4)));
typedef float f32x4 __attribute__((ext_vector_type(4)));

__device__ __forceinline__ bf16 f2bf(float f) { return (bf16)f; }
__device__ __forceinline__ bf16x8 ld8(const bf16* p) { return *(const bf16x8*)p; }
__device__ __forceinline__ f32x4 mfma16(bf16x8 a, bf16x8 b, f32x4 c) {
  return __builtin_amdgcn_mfma_f32_16x16x32_bf16(a, b, c, 0, 0, 0);
}

// ---------------- cast f32 -> bf16, vectorized x4 ----------------
__global__ void k_cast(const float* __restrict__ in, bf16* __restrict__ out, int n4) {
  int i = blockIdx.x * blockDim.x + threadIdx.x;
  int stride = gridDim.x * blockDim.x;
  for (; i < n4; i += stride) {
    float4 v = ((const float4*)in)[i];
    bf16x4 o;
    o[0] = f2bf(v.x); o[1] = f2bf(v.y); o[2] = f2bf(v.z); o[3] = f2bf(v.w);
    ((bf16x4*)out)[i] = o;
  }
}

// ---------------- GEMM: C[m][n] = sum_k A[m][k]*B[n][k] (C = A @ B^T) ----------------
template <typename CT>
__global__ __launch_bounds__(256) void k_gemm_bt(const bf16* __restrict__ A,
                                                 const bf16* __restrict__ B,
                                                 CT* __restrict__ C,
                                                 int M, int N, int K) {
  __shared__ bf16 As[128 * 64];
  __shared__ bf16 Bs[64 * 64];
  const int tid = threadIdx.x;
  const int l = tid & 63, w = tid >> 6;
  const int g = l >> 4, r15 = l & 15;
  const int m0 = blockIdx.y * 128, n0 = blockIdx.x * 64;
  const int wm = (w >> 1) * 64, wn = (w & 1) * 32;
  f32x4 acc[4][2] = {};
  for (int k0 = 0; k0 < K; k0 += 64) {
    __syncthreads();
#pragma unroll
    for (int i = 0; i < 4; i++) {
      int slot = tid + i * 256;
      int row = slot >> 3, cp = slot & 7;
      int gc = cp ^ (row & 7);
      *(uint4*)(As + slot * 8) = *(const uint4*)(A + (size_t)(m0 + row) * K + k0 + gc * 8);
    }
#pragma unroll
    for (int i = 0; i < 2; i++) {
      int slot = tid + i * 256;
      int row = slot >> 3, cp = slot & 7;
      int gc = cp ^ (row & 7);
      *(uint4*)(Bs + slot * 8) = *(const uint4*)(B + (size_t)(n0 + row) * K + k0 + gc * 8);
    }
    __syncthreads();
#pragma unroll
    for (int kk = 0; kk < 2; kk++) {
      bf16x8 af[4], bfr[2];
#pragma unroll
      for (int mi = 0; mi < 4; mi++) {
        int row = wm + mi * 16 + r15;
        int cidx = (kk * 4 + g) ^ (row & 7);
        af[mi] = *(const bf16x8*)(As + row * 64 + cidx * 8);
      }
#pragma unroll
      for (int ni = 0; ni < 2; ni++) {
        int row = wn + ni * 16 + r15;
        int cidx = (kk * 4 + g) ^ (row & 7);
        bfr[ni] = *(const bf16x8*)(Bs + row * 64 + cidx * 8);
      }
#pragma unroll
      for (int mi = 0; mi < 4; mi++)
#pragma unroll
        for (int ni = 0; ni < 2; ni++)
          acc[mi][ni] = mfma16(af[mi], bfr[ni], acc[mi][ni]);
    }
  }
#pragma unroll
  for (int mi = 0; mi < 4; mi++)
#pragma unroll
    for (int ni = 0; ni < 2; ni++)
#pragma unroll
      for (int rr = 0; rr < 4; rr++) {
        int mrow = m0 + wm + mi * 16 + g * 4 + rr;
        int ncol = n0 + wn + ni * 16 + r15;
        float v = acc[mi][ni][rr];
        if constexpr (sizeof(CT) == 4) C[(size_t)mrow * N + ncol] = v;
        else                           C[(size_t)mrow * N + ncol] = f2bf(v);
      }
}

// ---------------- transpose V (NC x SD) -> Vt (SD x NC) ----------------
__global__ __launch_bounds__(256) void k_transpose(const bf16* __restrict__ V, bf16* __restrict__ Vt) {
  __shared__ bf16 tile[32][33];
  const int t = threadIdx.x;
  const int col = t & 31, r0 = t >> 5;
  const int cbase = blockIdx.y * 32;
  const int dbase = blockIdx.x * 32;
#pragma unroll
  for (int i = 0; i < 4; i++) {
    int r = r0 + i * 8;
    tile[r][col] = V[(size_t)(cbase + r) * SD + dbase + col];
  }
  __syncthreads();
#pragma unroll
  for (int i = 0; i < 4; i++) {
    int r = r0 + i * 8;
    Vt[(size_t)(dbase + r) * NC + cbase + col] = tile[col][r];
  }
}

// ---------------- fused gated attention v2 ----------------
// grid (NS/128, NH, 4 c-chunks). 4 waves split s (32 rows each), share K/V LDS tiles.
// Swapped-operand scores: mfma(K,Q) -> lane holds s=r15 (col), c=g*4+rr (row).
// Unnormalized partials: Opart[ch][s][d] bf16, psum_part[ch][s][h] fp32.
__global__ __launch_bounds__(256) void k_attn2(const bf16* __restrict__ Q, const bf16* __restrict__ Km,
                                               const bf16* __restrict__ Vt, const float* __restrict__ Gf,
                                               float* __restrict__ psum_part, bf16* __restrict__ Opart) {
  __shared__ bf16 Kl[64 * 128];     // rows 256B (16 x 16B slots), swizzled
  __shared__ bf16 Vl[128 * 64];     // rows 128B (8 x 16B slots), swizzled
  __shared__ bf16 Pl[4][32 * 64];   // per-wave P tile, rows 128B, swizzled
  const int tid = threadIdx.x;
  const int l = tid & 63, w = tid >> 6;
  const int g = l >> 4, r15 = l & 15;
  const int s0 = blockIdx.x * 128;
  const int h = blockIdx.y, hoff = h * DK;
  const int ch = blockIdx.z;
  const int cbase = ch * (NC / 4);
  const float scale = 0.08838834764831845f;  // 1/sqrt(128)
  char* KlB = (char*)Kl;
  char* VlB = (char*)Vl;
  char* PlB = (char*)Pl[w];
  const int swz = r15 & 7;

  bf16x8 qf[2][4];
#pragma unroll
  for (int smi = 0; smi < 2; smi++)
#pragma unroll
    for (int kk = 0; kk < 4; kk++)
      qf[smi][kk] = ld8(Q + (size_t)(s0 + w * 32 + smi * 16 + r15) * SD + hoff + kk * 32 + g * 8);

  f32x4 oacc[8][2] = {};
  float psum[2] = {0.f, 0.f};

  const int krow0 = tid >> 4, ksl = tid & 15;  // K: 64 rows x 16 slots
  const int vrow0 = tid >> 3, vsl = tid & 7;   // V: 128 rows x 8 slots

  uint4 kreg[4], vreg[4];
  auto loadstep = [&](int cb) {
#pragma unroll
    for (int i = 0; i < 4; i++)
      kreg[i] = *(const uint4*)(Km + (size_t)(cb + krow0 + i * 16) * SD + hoff + ksl * 8);
#pragma unroll
    for (int i = 0; i < 4; i++)
      vreg[i] = *(const uint4*)(Vt + (size_t)(hoff + vrow0 + i * 32) * NC + cb + vsl * 8);
  };
  loadstep(cbase);

  for (int t = 0; t < 16; ++t) {
    const int cb = cbase + t * 64;
    __syncthreads();
#pragma unroll
    for (int i = 0; i < 4; i++) {
      int row = krow0 + i * 16;
      *(uint4*)(KlB + row * 256 + ((ksl ^ (row & 7)) << 4)) = kreg[i];
    }
#pragma unroll
    for (int i = 0; i < 4; i++) {
      int row = vrow0 + i * 32;
      *(uint4*)(VlB + row * 128 + ((vsl ^ (row & 7)) << 4)) = vreg[i];
    }
    __syncthreads();
    if (t < 15) loadstep(cb + 64);
    // ---- scores + gate + exp -> P (per-wave LDS) ----
#pragma unroll
    for (int csub = 0; csub < 4; ++csub) {
      bf16x8 kf[4];
#pragma unroll
      for (int kk = 0; kk < 4; kk++)
        kf[kk] = *(const bf16x8*)(KlB + (csub * 16 + r15) * 256 + (((kk * 4 + g) ^ swz) << 4));
#pragma unroll
      for (int smi = 0; smi < 2; smi++) {
        f32x4 a = {0.f, 0.f, 0.f, 0.f};
#pragma unroll
        for (int kk = 0; kk < 4; kk++) a = mfma16(kf[kk], qf[smi][kk], a);
        const int srow = s0 + w * 32 + smi * 16 + r15;
        float4 gv = *(const float4*)(Gf + (size_t)srow * NC + cb + csub * 16 + g * 4);
        float p0 = __expf(a[0] * scale * gv.x);
        float p1 = __expf(a[1] * scale * gv.y);
        float p2 = __expf(a[2] * scale * gv.z);
        float p3 = __expf(a[3] * scale * gv.w);
        psum[smi] += (p0 + p1) + (p2 + p3);
        bf16 pk[4] __attribute__((aligned(8)));
        pk[0] = f2bf(p0); pk[1] = f2bf(p1); pk[2] = f2bf(p2); pk[3] = f2bf(p3);
        *(uint2*)(PlB + (smi * 16 + r15) * 128 + ((csub * 32 + g * 8) ^ (swz << 4))) = *(const uint2*)pk;
      }
    }
    // ---- PV ----
#pragma unroll
    for (int kc = 0; kc < 2; ++kc) {
      bf16x8 pf[2];
#pragma unroll
      for (int smi = 0; smi < 2; smi++)
        pf[smi] = *(const bf16x8*)(PlB + (smi * 16 + r15) * 128 + ((kc * 64 + g * 16) ^ (swz << 4)));
#pragma unroll
      for (int nf = 0; nf < 8; ++nf) {
        bf16x8 vf = *(const bf16x8*)(VlB + (nf * 16 + r15) * 128 + (((kc * 4 + g) ^ swz) << 4));
#pragma unroll
        for (int smi = 0; smi < 2; smi++)
          oacc[nf][smi] = mfma16(vf, pf[smi], oacc[nf][smi]);
      }
    }
  }
  // ---- epilogue: psum partials + unnormalized O partials ----
#pragma unroll
  for (int smi = 0; smi < 2; smi++) {
    float ps = psum[smi];
    ps += __shfl_xor(ps, 16);
    ps += __shfl_xor(ps, 32);
    if (g == 0) {
      int srow = s0 + w * 32 + smi * 16 + r15;
      psum_part[((size_t)ch * NS + srow) * NH + h] = ps;
    }
  }
#pragma unroll
  for (int nf = 0; nf < 8; nf++)
#pragma unroll
    for (int smi = 0; smi < 2; smi++) {
      int srow = s0 + w * 32 + smi * 16 + r15;
      bf16 ob[4] __attribute__((aligned(8)));
#pragma unroll
      for (int rr = 0; rr < 4; rr++) ob[rr] = f2bf(oacc[nf][smi][rr]);
      *(uint2*)(Opart + ((size_t)ch * NS + srow) * SD + hoff + nf * 16 + g * 4) = *(const uint2*)ob;
    }
}

// ---------------- combine partials: normalize, emit Hattn (bf16) + inv_l ----------------
__global__ __launch_bounds__(256) void k_combine(const float* __restrict__ psum_part,
                                                 const bf16* __restrict__ Opart,
                                                 bf16* __restrict__ Hat, float* __restrict__ inv_l) {
  __shared__ float il_s[NH];
  const int row = blockIdx.x, t = threadIdx.x;
  if (t < NH) {
    float s = 0.f;
#pragma unroll
    for (int ch = 0; ch < 4; ch++) s += psum_part[((size_t)ch * NS + row) * NH + t];
    float iv = 1.0f / s;
    il_s[t] = iv;
    inv_l[(size_t)row * NH + t] = iv;
  }
  __syncthreads();
  const int d0 = t * 4;
  float acc[4] = {0.f, 0.f, 0.f, 0.f};
#pragma unroll
  for (int ch = 0; ch < 4; ch++) {
    bf16x4 v = *(const bf16x4*)(Opart + ((size_t)ch * NS + row) * SD + d0);
#pragma unroll
    for (int j = 0; j < 4; j++) acc[j] += (float)v[j];
  }
  float iv = il_s[d0 >> 7];
  bf16 ob[4] __attribute__((aligned(8)));
#pragma unroll
  for (int j = 0; j < 4; j++) ob[j] = f2bf(acc[j] * iv);
  *(uint2*)(Hat + (size_t)row * SD + d0) = *(const uint2*)ob;
}

// ---------------- attn.mean over heads v2 ----------------
// grid (NC/64, NS/64). 4 waves = 2x2 over (s64, c64). Per-head K/Q tiles staged in LDS.
__global__ __launch_bounds__(256) void k_mean2(const bf16* __restrict__ Q, const bf16* __restrict__ Km,
                                               const float* __restrict__ Gf, const float* __restrict__ inv_l,
                                               float* __restrict__ out_mean) {
  __shared__ bf16 Klm[64 * 128];
  __shared__ bf16 Qlm[64 * 128];
  const int tid = threadIdx.x;
  const int l = tid & 63, w = tid >> 6;
  const int g = l >> 4, r15 = l & 15;
  const int ws = w >> 1, wc = w & 1;
  const int c0 = blockIdx.x * 64, s0 = blockIdx.y * 64;
  const float scale = 0.08838834764831845f;
  const int swz = r15 & 7;
  char* KB = (char*)Klm;
  char* QB = (char*)Qlm;
  const int row0 = tid >> 4, sl = tid & 15;

  float4 gv[2][2];
#pragma unroll
  for (int smi = 0; smi < 2; smi++)
#pragma unroll
    for (int csub = 0; csub < 2; csub++)
      gv[smi][csub] = *(const float4*)(Gf + (size_t)(s0 + ws * 32 + smi * 16 + r15) * NC +
                                       c0 + wc * 32 + csub * 16 + g * 4);

  f32x4 macc[2][2] = {};
  uint4 kreg[4], qreg[4];
  auto loadh = [&](int h) {
#pragma unroll
    for (int i = 0; i < 4; i++)
      kreg[i] = *(const uint4*)(Km + (size_t)(c0 + row0 + i * 16) * SD + h * DK + sl * 8);
#pragma unroll
    for (int i = 0; i < 4; i++)
      qreg[i] = *(const uint4*)(Q + (size_t)(s0 + row0 + i * 16) * SD + h * DK + sl * 8);
  };
  loadh(0);
  for (int h = 0; h < NH; ++h) {
    __syncthreads();
#pragma unroll
    for (int i = 0; i < 4; i++) {
      int row = row0 + i * 16;
      *(uint4*)(KB + row * 256 + ((sl ^ (row & 7)) << 4)) = kreg[i];
    }
#pragma unroll
    for (int i = 0; i < 4; i++) {
      int row = row0 + i * 16;
      *(uint4*)(QB + row * 256 + ((sl ^ (row & 7)) << 4)) = qreg[i];
    }
    __syncthreads();
    if (h < NH - 1) loadh(h + 1);
    bf16x8 kf[2][4], qfr[2][4];
#pragma unroll
    for (int csub = 0; csub < 2; csub++)
#pragma unroll
      for (int kk = 0; kk < 4; kk++)
        kf[csub][kk] = *(const bf16x8*)(KB + (wc * 32 + csub * 16 + r15) * 256 + (((kk * 4 + g) ^ swz) << 4));
#pragma unroll
    for (int smi = 0; smi < 2; smi++)
#pragma unroll
      for (int kk = 0; kk < 4; kk++)
        qfr[smi][kk] = *(const bf16x8*)(QB + (ws * 32 + smi * 16 + r15) * 256 + (((kk * 4 + g) ^ swz) << 4));
    float ilv[2];
#pragma unroll
    for (int smi = 0; smi < 2; smi++)
      ilv[smi] = inv_l[(size_t)(s0 + ws * 32 + smi * 16 + r15) * NH + h];
#pragma unroll
    for (int smi = 0; smi < 2; smi++)
#pragma unroll
      for (int csub = 0; csub < 2; csub++) {
        f32x4 a = {0.f, 0.f, 0.f, 0.f};
#pragma unroll
        for (int kk = 0; kk < 4; kk++) a = mfma16(kf[csub][kk], qfr[smi][kk], a);
        float4 gvv = gv[smi][csub];
        macc[smi][csub][0] += __expf(a[0] * scale * gvv.x) * ilv[smi];
        macc[smi][csub][1] += __expf(a[1] * scale * gvv.y) * ilv[smi];
        macc[smi][csub][2] += __expf(a[2] * scale * gvv.z) * ilv[smi];
        macc[smi][csub][3] += __expf(a[3] * scale * gvv.w) * ilv[smi];
      }
  }
#pragma unroll
  for (int smi = 0; smi < 2; smi++)
#pragma unroll
    for (int csub = 0; csub < 2; csub++) {
      int srow = s0 + ws * 32 + smi * 16 + r15;
      float4 o;
      o.x = macc[smi][csub][0] * 0.125f;
      o.y = macc[smi][csub][1] * 0.125f;
      o.z = macc[smi][csub][2] * 0.125f;
      o.w = macc[smi][csub][3] * 0.125f;
      *(float4*)(out_mean + (size_t)srow * NC + c0 + wc * 32 + csub * 16 + g * 4) = o;
    }
}

// ---------------- residual + LayerNorm ----------------
__global__ __launch_bounds__(256) void k_ln(const float* __restrict__ Op, const float* __restrict__ HS,
                                            const float* __restrict__ bO, const float* __restrict__ gamma,
                                            const float* __restrict__ beta, float* __restrict__ out) {
  __shared__ float rs[4][2];
  const int row = blockIdx.x, t = threadIdx.x;
  const int l = t & 63, w = t >> 6;
  float4 xo = *(const float4*)(Op + (size_t)row * SD + t * 4);
  float4 hs = *(const float4*)(HS + (size_t)row * SD + t * 4);
  float4 bo = *(const float4*)(bO + t * 4);
  float x[4] = {xo.x + hs.x + bo.x, xo.y + hs.y + bo.y,
                xo.z + hs.z + bo.z, xo.w + hs.w + bo.w};
  float s = x[0] + x[1] + x[2] + x[3];
  float q = x[0] * x[0] + x[1] * x[1] + x[2] * x[2] + x[3] * x[3];
#pragma unroll
  for (int m = 1; m < 64; m <<= 1) { s += __shfl_xor(s, m); q += __shfl_xor(q, m); }
  if (l == 0) { rs[w][0] = s; rs[w][1] = q; }
  __syncthreads();
  s = rs[0][0] + rs[1][0] + rs[2][0] + rs[3][0];
  q = rs[0][1] + rs[1][1] + rs[2][1] + rs[3][1];
  float mean = s * (1.0f / SD);
  float var = q * (1.0f / SD) - mean * mean;
  float rstd = rsqrtf(var + 1e-5f);
  float4 gm = *(const float4*)(gamma + t * 4);
  float4 bt = *(const float4*)(beta + t * 4);
  float4 o;
  o.x = (x[0] - mean) * rstd * gm.x + bt.x;
  o.y = (x[1] - mean) * rstd * gm.y + bt.y;
  o.z = (x[2] - mean) * rstd * gm.z + bt.z;
  o.w = (x[3] - mean) * rstd * gm.w + bt.w;
  *(float4*)(out + (size_t)row * SD + t * 4) = o;
}

extern "C" void kernel_launch(void* const* d_in, const int* in_sizes, int n_in,
                              void* d_out, int out_size, void* d_ws, size_t ws_size,
                              hipStream_t stream) {
  const float* H_S = (const float*)d_in[0];
  const float* H_C = (const float*)d_in[1];
  const float* G   = (const float*)d_in[2];
  const float* W_Q = (const float*)d_in[3];
  const float* W_K = (const float*)d_in[4];
  const float* W_V = (const float*)d_in[5];
  const float* W_O = (const float*)d_in[6];
  const float* b_O = (const float*)d_in[7];
  const float* gam = (const float*)d_in[8];
  const float* bet = (const float*)d_in[9];
  float* out = (float*)d_out;                  // (NS, SD)
  float* out_mean = out + (size_t)NS * SD;     // (NS, NC)

  char* p = (char*)d_ws;
  auto alloc = [&](size_t bytes) { char* r = p; p += (bytes + 255) & ~(size_t)255; return r; };
  // region0: dead after QKV gemms + transpose; Opart aliases its base (16 MB of 20 MB)
  char* region0 = alloc((size_t)20 << 20);
  bf16* HSb = (bf16*)region0;                          // 4 MB
  bf16* HCb = (bf16*)(region0 + ((size_t)4 << 20));    // 4 MB
  bf16* WQb = (bf16*)(region0 + ((size_t)8 << 20));    // 2 MB
  bf16* WKb = (bf16*)(region0 + ((size_t)10 << 20));   // 1 MB
  bf16* WVb = (bf16*)(region0 + ((size_t)11 << 20));   // 1 MB
  bf16* Vb  = (bf16*)(region0 + ((size_t)12 << 20));   // 8 MB (NC x SD)
  bf16* Opart = (bf16*)region0;                        // 16 MB: 4 x NS x SD bf16
  bf16* WOb = (bf16*)alloc((size_t)SD * SD * 2);
  bf16* Qb  = (bf16*)alloc((size_t)NS * SD * 2);
  bf16* Kb  = (bf16*)alloc((size_t)NC * SD * 2);
  bf16* Vtb = (bf16*)alloc((size_t)SD * NC * 2);
  bf16* Hat = (bf16*)alloc((size_t)NS * SD * 2);
  float* Opj = (float*)alloc((size_t)NS * SD * 4);
  float* invl = (float*)alloc((size_t)NS * NH * 4);
  float* psum_part = (float*)alloc((size_t)4 * NS * NH * 4);

  k_cast<<<1024, 256, 0, stream>>>(H_S, HSb, NS * SD / 4);
  k_cast<<<1024, 256, 0, stream>>>(H_C, HCb, NC * BD / 4);
  k_cast<<<1024, 256, 0, stream>>>(W_Q, WQb, SD * SD / 4);
  k_cast<<<1024, 256, 0, stream>>>(W_K, WKb, SD * BD / 4);
  k_cast<<<1024, 256, 0, stream>>>(W_V, WVb, SD * BD / 4);
  k_cast<<<1024, 256, 0, stream>>>(W_O, WOb, SD * SD / 4);

  k_gemm_bt<bf16><<<dim3(SD / 64, NS / 128), 256, 0, stream>>>(HSb, WQb, Qb, NS, SD, SD);
  k_gemm_bt<bf16><<<dim3(SD / 64, NC / 128), 256, 0, stream>>>(HCb, WKb, Kb, NC, SD, BD);
  k_gemm_bt<bf16><<<dim3(SD / 64, NC / 128), 256, 0, stream>>>(HCb, WVb, Vb, NC, SD, BD);
  k_transpose<<<dim3(SD / 32, NC / 32), 256, 0, stream>>>(Vb, Vtb);

  k_attn2<<<dim3(NS / 128, NH, 4), 256, 0, stream>>>(Qb, Kb, Vtb, G, psum_part, Opart);
  k_combine<<<NS, 256, 0, stream>>>(psum_part, Opart, Hat, invl);
  k_mean2<<<dim3(NC / 64, NS / 64), 256, 0, stream>>>(Qb, Kb, G, invl, out_mean);

  k_gemm_bt<float><<<dim3(SD / 64, NS / 128), 256, 0, stream>>>(Hat, WOb, Opj, NS, SD, SD);
  k_ln<<<NS, 256, 0, stream>>>(Opj, H_S, b_O, gam, bet, out);
}